// Round 6
// baseline (247.194 us; speedup 1.0000x reference)
//
#include <hip/hip_runtime.h>
#include <hip/hip_bf16.h>

// Problem constants (match reference)
#define D_MODEL 1024
#define N_HEADS 16
#define HEAD_DIM 64
#define SEQ_T 2048
#define BATCH 4

#define SL2E 0.18033688011f   // 0.125 * log2(e), baked into Q at GEMM epilogue

typedef short s8v  __attribute__((ext_vector_type(8)));   // 8 x bf16 bits
typedef float f32x4 __attribute__((ext_vector_type(4)));
typedef unsigned long long ull;

static __device__ __forceinline__ unsigned short f2bf(float f) {
  union { float f; unsigned int u; } v; v.f = f;
  unsigned int u = v.u;
  return (unsigned short)((u + 0x7FFF + ((u >> 16) & 1)) >> 16);  // RNE
}

// pack 2 f32 -> 2 bf16 in one instr (RNE); no builtin on gfx950, inline asm
static __device__ __forceinline__ unsigned int cvtpk_bf16(float lo, float hi) {
  unsigned int r;
  asm("v_cvt_pk_bf16_f32 %0, %1, %2" : "=v"(r) : "v"(lo), "v"(hi));
  return r;
}

#if __has_builtin(__builtin_amdgcn_exp2f)
#define EXP2(x) __builtin_amdgcn_exp2f(x)
#else
#define EXP2(x) exp2f(x)
#endif

// async global->LDS, 16B per lane; LDS dest = wave-uniform base + lane*16
static __device__ __forceinline__ void glds16(const void* g, void* l) {
  __builtin_amdgcn_global_load_lds(
      (const __attribute__((address_space(1))) void*)g,
      (__attribute__((address_space(3))) void*)l, 16, 0, 0);
}

// raw barrier (no compiler-inserted vmcnt(0) drain) + compiler memory fence
#define BARRIER() do { asm volatile("" ::: "memory"); \
                       __builtin_amdgcn_s_barrier();  \
                       asm volatile("" ::: "memory"); } while (0)

// one MFMA quadrant: 4 m-frags x 2 n-frags x 2 kk = 16 MFMA, setprio-wrapped
#define MFMA_Q(ACC, AF, BF) do {                                            \
    __builtin_amdgcn_s_setprio(1);                                          \
    _Pragma("unroll") for (int f_ = 0; f_ < 4; ++f_)                        \
      _Pragma("unroll") for (int g_ = 0; g_ < 2; ++g_)                      \
        _Pragma("unroll") for (int kk_ = 0; kk_ < 2; ++kk_)                 \
          ACC[f_][g_] = __builtin_amdgcn_mfma_f32_16x16x32_bf16(            \
              AF[f_][kk_], BF[g_][kk_], ACC[f_][g_], 0, 0, 0);              \
    __builtin_amdgcn_s_setprio(0);                                          \
  } while (0)

// ---------------------------------------------------------------------------
// bf16 MFMA GEMM — 256x256 tile, 8-phase counted-vmcnt schedule (faithful
// port of the m201 template): BK=64, 512 thr = 8 waves (2M x 4N), per-wave
// output 128x64, LDS 128 KB (2 dbuf x {A,B} x 2 halves x 128x64 bf16).
// Wave rows = mq*128 + wm*64, cols = nq*128 + wn*32  ==> each phase's
// quadrant (mq,nq) consumes exactly one A-half / one B-half uniformly
// across all waves.  Per K-tile (4 phases):
//   ph0: read A-h0(8)+B-h0(4); stage A-h1(t+1)->buf^1; bar; lgkm0; 16 MFMA(0,0); bar
//   ph1: read B-h1(4);         stage A-h0(t+2)->buf;   bar; lgkm0; 16 MFMA(0,1); bar
//   ph2: read A-h1(8);         stage B-h0(t+2)->buf;   bar; lgkm0; 16 MFMA(1,1); bar
//   ph3:                       stage B-h1(t+2)->buf;   bar;        16 MFMA(1,0);
//        vmcnt(6) [tail: vmcnt(0)]; bar
// vmcnt ledger (per wave, 2 loads/stage): at ph3-end outstanding = prev
// tile's 3 stages + this tile's 4 = 14 loads; vmcnt(6) drains exactly tile
// (t+1)'s 4 halves, keeps tile (t+2)'s 3 halves in flight (steady state).
// Stage-target safety: each target's reads were issued in the previous
// phase and serviced before that phase's 2nd barrier (lgkmcnt(0) precedes
// MFMA precedes barrier); stages are issued after it.
//   MODE 0: fp32 out. MODE 1: QKV split — Q cols (<1024) pre-scaled by SL2E
//   into qkb; K cols (1024..2047) into qkb; V cols -> vT [bh][d][T] b64-packed.
// ---------------------------------------------------------------------------
template<int MODE>
__global__ __launch_bounds__(512, 2) void gemm_bt_kernel(
    const unsigned short* __restrict__ A, const unsigned short* __restrict__ Bt,
    const float* __restrict__ bias, float* __restrict__ Cout,
    unsigned short* __restrict__ qkb, unsigned short* __restrict__ vT,
    int M, int N, int K)
{
  __shared__ unsigned short As[2][2][128 * 64];   // [buf][half] 64 KB
  __shared__ unsigned short Bs[2][2][128 * 64];   // [buf][half] 64 KB

  const int tid  = threadIdx.x;
  const int lane = tid & 63;
  const int wid  = tid >> 6;
  const int col  = lane & 15;
  const int quad = lane >> 4;
  const int cx   = col & 7;
  const int wm   = wid >> 2;        // 0..1 (M direction, 64 rows within half)
  const int wn   = wid & 3;         // 0..3 (N direction, 32 cols within half)
  const int bm0  = blockIdx.y * 256;
  const int bn0  = blockIdx.x * 256;
  const int NT   = K >> 6;          // K-tiles (16 for K=1024)

  f32x4 a00[4][2], a01[4][2], a11[4][2], a10[4][2];
  #pragma unroll
  for (int f = 0; f < 4; ++f)
    #pragma unroll
    for (int g = 0; g < 2; ++g) {
      a00[f][g] = (f32x4)0.f; a01[f][g] = (f32x4)0.f;
      a11[f][g] = (f32x4)0.f; a10[f][g] = (f32x4)0.f;
    }

  // stage one 128-row half-tile (2 glds16/thread = 16 KB)
  auto stageA = [&](int t, int bb, int h) {
    const int k0 = t * 64;
    #pragma unroll
    for (int l = 0; l < 2; ++l) {
      int idx = l * 512 + tid;                  // [0,1024)
      int row = idx >> 3;                       // [0,128)
      int gc  = (idx & 7) ^ (row & 7);          // XOR k-chunk swizzle
      glds16(A + (size_t)(bm0 + h * 128 + row) * K + k0 + gc * 8,
             &As[bb][h][idx * 8]);
    }
  };
  auto stageB = [&](int t, int bb, int h) {
    const int k0 = t * 64;
    #pragma unroll
    for (int l = 0; l < 2; ++l) {
      int idx = l * 512 + tid;
      int row = idx >> 3;
      int gc  = (idx & 7) ^ (row & 7);
      glds16(Bt + (size_t)(bn0 + h * 128 + row) * K + k0 + gc * 8,
             &Bs[bb][h][idx * 8]);
    }
  };

  s8v af[4][2], b0[2][2], b1[2][2];
  auto ldA = [&](int bb, int mq, s8v (&dst)[4][2]) {
    #pragma unroll
    for (int f = 0; f < 4; ++f)
      #pragma unroll
      for (int kk = 0; kk < 2; ++kk)
        dst[f][kk] = *(const s8v*)&As[bb][mq][(wm * 64 + f * 16 + col) * 64 +
                                              (((kk * 4 + quad) ^ cx) * 8)];
  };
  auto ldB = [&](int bb, int nq, s8v (&dst)[2][2]) {
    #pragma unroll
    for (int g = 0; g < 2; ++g)
      #pragma unroll
      for (int kk = 0; kk < 2; ++kk)
        dst[g][kk] = *(const s8v*)&Bs[bb][nq][(wn * 32 + g * 16 + col) * 64 +
                                              (((kk * 4 + quad) ^ cx) * 8)];
  };

  // prologue: tile0 complete (4 halves FIRST in FIFO), tile1 minus A-h1.
  // 7 stages = 14 loads; vmcnt(6) drains the oldest 8 = tile0 resident.
  stageA(0, 0, 0); stageA(0, 0, 1); stageB(0, 0, 0); stageB(0, 0, 1);
  stageA(1, 1, 0); stageB(1, 1, 0); stageB(1, 1, 1);
  asm volatile("s_waitcnt vmcnt(6)" ::: "memory");
  BARRIER();

  for (int t = 0; t < NT; ++t) {
    const int bb = t & 1;
    const bool s2 = (t + 2 < NT);

    // ---- phase 0: quadrant (0,0) ----
    ldA(bb, 0, af); ldB(bb, 0, b0);
    if (t + 1 < NT) stageA(t + 1, bb ^ 1, 1);   // A-h1(t+1) completes next tile
    BARRIER();
    asm volatile("s_waitcnt lgkmcnt(0)" ::: "memory");
    MFMA_Q(a00, af, b0);
    BARRIER();

    // ---- phase 1: quadrant (0,1) ----
    ldB(bb, 1, b1);
    if (s2) stageA(t + 2, bb, 0);
    BARRIER();
    asm volatile("s_waitcnt lgkmcnt(0)" ::: "memory");
    MFMA_Q(a01, af, b1);
    BARRIER();

    // ---- phase 2: quadrant (1,1) ----
    ldA(bb, 1, af);
    if (s2) stageB(t + 2, bb, 0);
    BARRIER();
    asm volatile("s_waitcnt lgkmcnt(0)" ::: "memory");
    MFMA_Q(a11, af, b1);
    BARRIER();

    // ---- phase 3: quadrant (1,0), counted vmcnt once per K-tile ----
    if (s2) stageB(t + 2, bb, 1);
    BARRIER();
    MFMA_Q(a10, af, b0);
    if (t + 1 < NT) {
      if (s2) asm volatile("s_waitcnt vmcnt(6)" ::: "memory");
      else    asm volatile("s_waitcnt vmcnt(0)" ::: "memory");
    }
    BARRIER();
  }

  // ------------------------------ epilogue -------------------------------
  auto epi = [&](const f32x4 (&Aq)[4][2], int mq, int nq) {
    if (MODE == 1 && bn0 >= 2048) {
      // V epilogue: packed b64 stores into vT [bh][d][T]
      #pragma unroll
      for (int f = 0; f < 4; ++f) {
        int m_base = bm0 + mq * 128 + wm * 64 + f * 16 + quad * 4;
        #pragma unroll
        for (int g = 0; g < 2; ++g) {
          int n  = bn0 + nq * 128 + wn * 32 + g * 16 + col;
          float bvv = bias[n];
          int hd = n - 2048;                     // h*64 + d
          size_t bh = (size_t)(bm0 >> 11) * 16 + (hd >> 6);
          ull pk = (ull)f2bf(Aq[f][g][0] + bvv)
                 | ((ull)f2bf(Aq[f][g][1] + bvv) << 16)
                 | ((ull)f2bf(Aq[f][g][2] + bvv) << 32)
                 | ((ull)f2bf(Aq[f][g][3] + bvv) << 48);
          *(ull*)(vT + (bh * 64 + (hd & 63)) * 2048 + (m_base & 2047)) = pk;
        }
      }
    } else {
      const float sc = (MODE == 1 && bn0 < 1024) ? SL2E : 1.0f;  // Q pre-scale
      #pragma unroll
      for (int f = 0; f < 4; ++f) {
        #pragma unroll
        for (int r = 0; r < 4; ++r) {
          size_t m = bm0 + mq * 128 + wm * 64 + f * 16 + quad * 4 + r;
          #pragma unroll
          for (int g = 0; g < 2; ++g) {
            int n = bn0 + nq * 128 + wn * 32 + g * 16 + col;
            float v = Aq[f][g][r] + bias[n];
            if (MODE == 0) Cout[m * N + n] = v;
            else           qkb[m * 2048 + n] = f2bf(v * sc);
          }
        }
      }
    }
  };
  epi(a00, 0, 0); epi(a01, 0, 1); epi(a11, 1, 1); epi(a10, 1, 0);
}

// ---------------------------------------------------------------------------
// Merged prep: x cast (blocks 0..8191), W_qkv transpose (8192..11263),
// W_proj transpose (11264..12287).
// ---------------------------------------------------------------------------
static __device__ __forceinline__ void transpose_tile(
    const float* __restrict__ W, unsigned short* __restrict__ Wt,
    int K, int N, int n0, int k0)
{
  __shared__ float tile[32][33];
  const int tx = threadIdx.x & 31, ty = threadIdx.x >> 5;
  #pragma unroll
  for (int i = 0; i < 4; ++i)
    tile[ty + i * 8][tx] = W[(size_t)(k0 + ty + i * 8) * N + n0 + tx];
  __syncthreads();
  #pragma unroll
  for (int i = 0; i < 4; ++i)
    Wt[(size_t)(n0 + ty + i * 8) * K + k0 + tx] = f2bf(tile[tx][ty + i * 8]);
}

__global__ __launch_bounds__(256) void prep_kernel(
    const float* __restrict__ x, const float* __restrict__ W_qkv,
    const float* __restrict__ W_proj, ushort4* __restrict__ xb,
    unsigned short* __restrict__ wqt, unsigned short* __restrict__ wpt)
{
  const int bid = blockIdx.x;
  if (bid < 8192) {
    int i = bid * 256 + threadIdx.x;
    float4 v = ((const float4*)x)[i];
    ushort4 o;
    o.x = f2bf(v.x); o.y = f2bf(v.y); o.z = f2bf(v.z); o.w = f2bf(v.w);
    xb[i] = o;
  } else if (bid < 8192 + 3072) {
    int b2 = bid - 8192;                      // W_qkv [1024, 3072] -> wqt
    transpose_tile(W_qkv, wqt, 1024, 3072, (b2 % 96) * 32, (b2 / 96) * 32);
  } else {
    int b3 = bid - 11264;                     // W_proj [1024, 1024] -> wpt
    transpose_tile(W_proj, wpt, 1024, 1024, (b3 % 32) * 32, (b3 / 32) * 32);
  }
}

// ---------------------------------------------------------------------------
// bf16 MFMA flash causal attention — QT=256, 8 waves (512 thr), KT=64,
// async dbuf, fixed-max softmax, TRANSPOSED-S + k-interleaved K-row
// permutation (round-5 proven; P never touches LDS).
// ---------------------------------------------------------------------------
__global__ __launch_bounds__(512, 4) void attn_mfma_kernel(
    const unsigned short* __restrict__ qk, const unsigned short* __restrict__ vT,
    unsigned short* __restrict__ y)
{
  __shared__ unsigned short Ks[2][64 * 64];   // 16 KB
  __shared__ unsigned short Vs[2][64 * 64];   // 16 KB   (total 32 KB)

  const int tid  = threadIdx.x;
  const int wave = tid >> 6;
  const int lane = tid & 63;
  const int col  = lane & 15;
  const int quad = lane >> 4;
  const int cx   = col & 7;

  const int bh = blockIdx.x;
  const int b = bh >> 4, h = bh & 15;
  // pair-balanced qblk order: y=0..3 -> 7,6,5,4 (dispatched first), y=4..7 -> 0,1,2,3
  const int yy = (int)blockIdx.y;
  const int qblk = (yy < 4) ? (7 - yy) : (yy - 4);
  const int q0 = qblk * 256;
  const int nk = 4 * qblk + 4;
  const int C2 = 2048;

  const unsigned short* qbase = qk + (size_t)b * SEQ_T * C2 + h * 64;
  const unsigned short* kbase = qbase + 1024;
  const unsigned short* vbase = vT + (size_t)bh * 64 * 2048;

  // Q fragments for both stripes (B-operand: rows of Q, pre-scaled by SL2E)
  s8v qf[2][2];
  #pragma unroll
  for (int s = 0; s < 2; ++s)
    #pragma unroll
    for (int c = 0; c < 2; ++c)
      qf[s][c] = *(const s8v*)(qbase +
          (size_t)(q0 + s * 128 + wave * 16 + col) * C2 + c * 32 + quad * 8);

  f32x4 acc[2][4];
  #pragma unroll
  for (int s = 0; s < 2; ++s)
    #pragma unroll
    for (int t = 0; t < 4; ++t) acc[s][t] = (f32x4)0.f;
  float lsum[2] = {0.f, 0.f};                // per-lane partial row sum, q=col

  // 512 threads: exactly one glds16 per thread per tile (K and V)
  // K uses sigma(row) = (row&7)^((row>>1)&4); V keeps (row&7)
  auto stage = [&](int kt, int bi) {
    const int k0 = kt * 64;
    int row = tid >> 3;
    int gk  = (tid & 7) ^ (row & 7) ^ ((row >> 1) & 4);
    int gv  = (tid & 7) ^ (row & 7);
    glds16(kbase + (size_t)(k0 + row) * C2 + gk * 8, &Ks[bi][tid * 8]);
    glds16(vbase + (size_t)row * 2048 + k0 + gv * 8, &Vs[bi][tid * 8]);
  };

  auto tile_body = [&](int kt, int bi) {
    const int k0 = kt * 64;

    // K fragments, k-interleaved row permutation (A-operand)
    s8v kf[4][2];
    const int pbase = (col >> 2) * 8 + (col & 3);
    #pragma unroll
    for (int t = 0; t < 4; ++t) {
      const int rowt = pbase + (t & 1) * 4 + (t >> 1) * 32;
      const int sx   = (rowt & 7) ^ ((rowt >> 1) & 4);
      #pragma unroll
      for (int c = 0; c < 2; ++c)
        kf[t][c] = *(const s8v*)&Ks[bi][rowt * 64 + (((c * 4 + quad) ^ sx) * 8)];
    }

    // pass 1: QK^T + softmax per stripe; P stays in registers (pf)
    s8v pf[2][2];
    bool live[2];
    #pragma unroll
    for (int s = 0; s < 2; ++s) {
      const int qs = q0 + s * 128 + wave * 16;
      live[s] = (k0 <= qs + 15);
      if (!live[s]) continue;

      f32x4 st[4];
      #pragma unroll
      for (int t = 0; t < 4; ++t) st[t] = (f32x4)0.f;
      #pragma unroll
      for (int t = 0; t < 4; ++t)
        #pragma unroll
        for (int c = 0; c < 2; ++c)
          st[t] = __builtin_amdgcn_mfma_f32_16x16x32_bf16(kf[t][c], qf[s][c], st[t], 0, 0, 0);

      // lane (col,quad) holds P[q=qs+col][k0 + 8*quad + r + 4*(t&1) + 32*(t>>1)]
      uint2 pw[4];
      const bool diag = (k0 + 63 > qs);       // wave-uniform
      if (!diag) {
        #pragma unroll
        for (int t = 0; t < 4; ++t) {
          float e0 = EXP2(st[t][0]);
          float e1 = EXP2(st[t][1]);
          float e2 = EXP2(st[t][2]);
          float e3 = EXP2(st[t][3]);
          lsum[s] += (e0 + e1) + (e2 + e3);
          pw[t].x = cvtpk_bf16(e0, e1);
          pw[t].y = cvtpk_bf16(e2, e3);
        }
      } else {
        const int qg = qs + col;
        #pragma unroll
        for (int t = 0; t < 4; ++t) {
          const int kt0 = k0 + 4 * (t & 1) + 32 * (t >> 1);
          if (kt0 > qs + 15) {                // chunk fully masked (uniform)
            pw[t].x = 0u; pw[t].y = 0u;
          } else {
            const int kq = kt0 + 8 * quad;
            float e[4];
            #pragma unroll
            for (int r = 0; r < 4; ++r) {
              float v = EXP2(st[t][r]);
              if (kq + r > qg) v = 0.f;
              e[r] = v;
            }
            lsum[s] += (e[0] + e[1]) + (e[2] + e[3]);
            pw[t].x = cvtpk_bf16(e[0], e[1]);
            pw[t].y = cvtpk_bf16(e[2], e[3]);
          }
        }
      }
      // pf[c] = P chunk k = c*32 + quad*8 + {0..7}  (all lane-local)
      #pragma unroll
      for (int c = 0; c < 2; ++c) {
        union { uint4 u; s8v v; } cc;
        cc.u.x = pw[2 * c].x;  cc.u.y = pw[2 * c].y;
        cc.u.z = pw[2 * c + 1].x;  cc.u.w = pw[2 * c + 1].y;
        pf[s][c] = cc.v;
      }
    }

    // pass 2: V^T fragments (B-operand, rows d = t*16+col), then O += P·V^T
    s8v vf[4][2];
    #pragma unroll
    for (int t = 0; t < 4; ++t)
      #pragma unroll
      for (int c = 0; c < 2; ++c)
        vf[t][c] = *(const s8v*)&Vs[bi][(t * 16 + col) * 64 + (((c * 4 + quad) ^ cx) * 8)];
    #pragma unroll
    for (int s = 0; s < 2; ++s) {
      if (!live[s]) continue;
      #pragma unroll
      for (int t = 0; t < 4; ++t)
        #pragma unroll
        for (int c = 0; c < 2; ++c)
          acc[s][t] = __builtin_amdgcn_mfma_f32_16x16x32_bf16(pf[s][c], vf[t][c], acc[s][t], 0, 0, 0);
    }
  };

  stage(0, 0);
  for (int kt = 0; kt < nk; kt += 2) {
    __syncthreads();                               // buf0 staged & visible
    if (kt + 1 < nk) stage(kt + 1, 1);             // prefetch overlaps compute
    tile_body(kt, 0);
    if (kt + 1 < nk) {
      __syncthreads();                             // buf1 staged & visible
      if (kt + 2 < nk) stage(kt + 2, 0);
      tile_body(kt + 1, 1);
    }
  }

  // epilogue: reduce row sums across quads, broadcast per q, write y (bf16)
  #pragma unroll
  for (int s = 0; s < 2; ++s) {
    float v = lsum[s];
    v += __shfl_xor(v, 16);
    v += __shfl_xor(v, 32);                        // full sum for q = qs+col
    #pragma unroll
    for (int r = 0; r < 4; ++r) {
      float inv = 1.0f / __shfl(v, quad * 4 + r);  // sum for q-local quad*4+r
      int q = q0 + s * 128 + wave * 16 + quad * 4 + r;
      unsigned short* yrow = y + (size_t)(b * SEQ_T + q) * D_MODEL + h * 64;
      #pragma unroll
      for (int t = 0; t < 4; ++t)
        yrow[t * 16 + col] = f2bf(acc[s][t][r] * inv);
    }
  }
}

// ---------------------------------------------------------------------------
extern "C" void kernel_launch(void* const* d_in, const int* in_sizes, int n_in,
                              void* d_out, int out_size, void* d_ws, size_t ws_size,
                              hipStream_t stream) {
  const float* x      = (const float*)d_in[0];
  const float* W_qkv  = (const float*)d_in[1];
  const float* b_qkv  = (const float*)d_in[2];
  const float* W_proj = (const float*)d_in[3];
  const float* b_proj = (const float*)d_in[4];
  float* out = (float*)d_out;

  const int M  = BATCH * SEQ_T;    // 8192
  const int C  = D_MODEL;          // 1024
  const int C3 = 3 * D_MODEL;      // 3072

  // workspace (bf16 = unsigned short), total ~88 MB
  unsigned short* xb  = (unsigned short*)d_ws;           // [M, C]      16 MB
  unsigned short* wqt = xb  + (size_t)M * C;             // [3C, C]      6 MB
  unsigned short* wpt = wqt + (size_t)C3 * C;            // [C, C]       2 MB
  unsigned short* qkb = wpt + (size_t)C * C;             // [M, 2C]     32 MB
  unsigned short* vTb = qkb + (size_t)M * 2 * C;         // [64,64,T]   16 MB
  unsigned short* yb  = vTb + (size_t)64 * 64 * SEQ_T;   // [M, C]      16 MB

  // 0) merged prep: cast x, transpose-cast both weights
  prep_kernel<<<dim3(8192 + 3072 + 1024), dim3(256), 0, stream>>>(
      x, W_qkv, W_proj, (ushort4*)xb, wqt, wpt);

  // 1) qkv GEMM: 256x256 8-phase; 12 x 32 = 384 blocks
  gemm_bt_kernel<1><<<dim3(C3 / 256, M / 256), dim3(512), 0, stream>>>(
      xb, wqt, b_qkv, nullptr, qkb, vTb, M, C3, C);

  // 2) causal flash attention: QT=256, 512 thr, P in registers (no Ps LDS)
  attn_mfma_kernel<<<dim3(BATCH * N_HEADS, SEQ_T / 256), dim3(512), 0, stream>>>(
      qkb, vTb, yb);

  // 3) out = y @ W_proj + b_proj (fp32); 4 x 32 = 128 blocks (co-resident)
  gemm_bt_kernel<0><<<dim3(C / 256, M / 256), dim3(512), 0, stream>>>(
      yb, wpt, b_proj, out, nullptr, nullptr, M, C, C);
}